// Round 1
// baseline (2373.086 us; speedup 1.0000x reference)
//
#include <hip/hip_runtime.h>
#include <cstddef>
#include <cstdint>

#define NH 9

static const int cN1 = 100000, cN2 = 25000, cN3 = 6250;
static const int cE1 = 1200000, cE2 = 300000, cE3 = 75000;

static inline unsigned ceil_div(size_t a, size_t b) { return (unsigned)((a + b - 1) / b); }

// ---------------- generic fp32 GEMM: C[M,N] = A[M,K](lda) @ B[K,N](ldb) ----------------
__global__ __launch_bounds__(256) void gemm_f32(
    const float* __restrict__ A, int lda,
    const float* __restrict__ B, int ldb,
    float* __restrict__ C, int ldc,
    int M, int N, int K)
{
    const int BM = 64, BN = 64, BK = 16;
    __shared__ float As[BK][BM + 1];
    __shared__ float Bs[BK][BN + 1];
    const int tid = threadIdx.x;
    const int tx = tid & 15, ty = tid >> 4;
    const int row0 = blockIdx.y * BM, col0 = blockIdx.x * BN;
    float acc[4][4] = {};
    for (int k0 = 0; k0 < K; k0 += BK) {
        for (int l = tid; l < BM * BK; l += 256) {
            int r = l >> 4, c = l & 15;
            float v = 0.f;
            if (row0 + r < M && k0 + c < K) v = A[(size_t)(row0 + r) * lda + (k0 + c)];
            As[c][r] = v;
        }
        for (int l = tid; l < BK * BN; l += 256) {
            int r = l >> 6, c = l & 63;
            float v = 0.f;
            if (k0 + r < K && col0 + c < N) v = B[(size_t)(k0 + r) * ldb + (col0 + c)];
            Bs[r][c] = v;
        }
        __syncthreads();
#pragma unroll
        for (int kk = 0; kk < BK; ++kk) {
            float a[4], b[4];
#pragma unroll
            for (int i = 0; i < 4; ++i) a[i] = As[kk][ty * 4 + i];
#pragma unroll
            for (int j = 0; j < 4; ++j) b[j] = Bs[kk][tx * 4 + j];
#pragma unroll
            for (int i = 0; i < 4; ++i)
#pragma unroll
                for (int j = 0; j < 4; ++j) acc[i][j] += a[i] * b[j];
        }
        __syncthreads();
    }
#pragma unroll
    for (int i = 0; i < 4; ++i) {
        int r = row0 + ty * 4 + i;
        if (r >= M) break;
#pragma unroll
        for (int j = 0; j < 4; ++j) {
            int c = col0 + tx * 4 + j;
            if (c < N) C[(size_t)r * ldc + c] = acc[i][j];
        }
    }
}

// ---------------- per-edge attention + message + atomic aggregate ----------------
template <int OUT>
__global__ __launch_bounds__(256) void feast_edge(
    const int* __restrict__ src, const int* __restrict__ dst, int E,
    const float* __restrict__ xu, const float* __restrict__ xw,
    const float* __restrict__ cvec, float* __restrict__ agg)
{
    size_t tid = (size_t)blockIdx.x * 256 + threadIdx.x;
    int e = (int)(tid / OUT);
    int o = (int)(tid % OUT);
    if (e >= E) return;
    int s = src[e], d = dst[e];
    float t[NH];
    float m = -1e30f;
#pragma unroll
    for (int h = 0; h < NH; ++h) {
        t[h] = xu[s * NH + h] - xu[d * NH + h] + cvec[h];
        m = fmaxf(m, t[h]);
    }
    float den = 0.f;
#pragma unroll
    for (int h = 0; h < NH; ++h) { t[h] = __expf(t[h] - m); den += t[h]; }
    float inv = 1.f / den;
    const float* xws = xw + (size_t)s * (NH * OUT) + o;
    float msg = 0.f;
#pragma unroll
    for (int h = 0; h < NH; ++h) msg += t[h] * xws[h * OUT];
    atomicAdd(&agg[(size_t)d * OUT + o], msg * inv);
}

// ---------------- self-loop + mean + bias + (leaky relu), strided output ----------------
template <int OUT>
__global__ __launch_bounds__(256) void feast_finalize(
    const float* __restrict__ agg, const float* __restrict__ xw,
    const float* __restrict__ cvec, const float* __restrict__ bias,
    const int* __restrict__ indeg, float* __restrict__ outp,
    int n, int ldo, int col0, int act)
{
    size_t tid = (size_t)blockIdx.x * 256 + threadIdx.x;
    int i = (int)(tid / OUT);
    int o = (int)(tid % OUT);
    if (i >= n) return;
    float t[NH];
    float m = -1e30f;
#pragma unroll
    for (int h = 0; h < NH; ++h) { t[h] = cvec[h]; m = fmaxf(m, t[h]); }
    float den = 0.f;
#pragma unroll
    for (int h = 0; h < NH; ++h) { t[h] = __expf(t[h] - m); den += t[h]; }
    float inv = 1.f / den;
    const float* xws = xw + (size_t)i * (NH * OUT) + o;
    float msg = 0.f;
#pragma unroll
    for (int h = 0; h < NH; ++h) msg += t[h] * xws[h * OUT];
    msg *= inv;
    float v = (agg[(size_t)i * OUT + o] + msg) / (float)(indeg[i] + 1) + bias[o];
    if (act) v = v > 0.f ? v : 0.1f * v;
    outp[(size_t)i * ldo + col0 + o] = v;
}

// ---------------- misc ----------------
__global__ void count_idx(const int* __restrict__ idx, int n, int* __restrict__ cnt)
{
    int i = blockIdx.x * 256 + threadIdx.x;
    if (i < n) atomicAdd(&cnt[idx[i]], 1);
}

__global__ void pool_scatter(const float* __restrict__ xin, int ldx, const int* __restrict__ clust,
                             float* __restrict__ pooled, int C, int n)
{
    size_t tid = (size_t)blockIdx.x * 256 + threadIdx.x;
    int i = (int)(tid / C), c = (int)(tid % C);
    if (i >= n) return;
    atomicAdd(&pooled[(size_t)clust[i] * C + c], xin[(size_t)i * ldx + c]);
}

__global__ void pool_div(float* __restrict__ pooled, const int* __restrict__ pcnt, int C, int m)
{
    size_t tid = (size_t)blockIdx.x * 256 + threadIdx.x;
    int j = (int)(tid / C);
    if (j >= m) return;
    pooled[tid] /= fmaxf((float)pcnt[j], 1.f);
}

__global__ void gather_rows(const float* __restrict__ xin, int ldx, const int* __restrict__ idx,
                            float* __restrict__ outp, int C, int n)
{
    size_t tid = (size_t)blockIdx.x * 256 + threadIdx.x;
    int i = (int)(tid / C), c = (int)(tid % C);
    if (i >= n) return;
    outp[tid] = xin[(size_t)idx[i] * ldx + c];
}

// ---------------- fused FC head: lrelu(y@W1+b1) @ W2 + b2, row-normalize ----------------
__global__ __launch_bounds__(256) void fc_head(
    const float* __restrict__ yin, const float* __restrict__ w1, const float* __restrict__ b1,
    const float* __restrict__ w2, const float* __restrict__ b2,
    float* __restrict__ outp, int n)
{
    __shared__ float xs[16][32];
    __shared__ float w2s[1024 * 3];
    const int tid = threadIdx.x;
    const int node0 = blockIdx.x * 16;
    for (int l = tid; l < 16 * 32; l += 256) {
        int i = l >> 5, c = l & 31;
        int node = node0 + i;
        xs[i][c] = (node < n) ? yin[(size_t)node * 32 + c] : 0.f;
    }
    for (int l = tid; l < 1024 * 3; l += 256) w2s[l] = w2[l];
    __syncthreads();
    const int wave = tid >> 6, lane = tid & 63;
    float acc[4][3] = {};
#pragma unroll 1
    for (int ki = 0; ki < 16; ++ki) {
        int k = ki * 64 + lane;
        float bb = b1[k];
        float h0 = bb, h1 = bb, h2 = bb, h3 = bb;
#pragma unroll
        for (int c2 = 0; c2 < 32; ++c2) {
            float w = w1[c2 * 1024 + k];
            h0 += xs[wave * 4 + 0][c2] * w;
            h1 += xs[wave * 4 + 1][c2] * w;
            h2 += xs[wave * 4 + 2][c2] * w;
            h3 += xs[wave * 4 + 3][c2] * w;
        }
        h0 = h0 > 0.f ? h0 : 0.1f * h0;
        h1 = h1 > 0.f ? h1 : 0.1f * h1;
        h2 = h2 > 0.f ? h2 : 0.1f * h2;
        h3 = h3 > 0.f ? h3 : 0.1f * h3;
#pragma unroll
        for (int j = 0; j < 3; ++j) {
            float wv = w2s[k * 3 + j];
            acc[0][j] += h0 * wv;
            acc[1][j] += h1 * wv;
            acc[2][j] += h2 * wv;
            acc[3][j] += h3 * wv;
        }
    }
#pragma unroll
    for (int i = 0; i < 4; ++i)
#pragma unroll
        for (int j = 0; j < 3; ++j) {
            float v = acc[i][j];
#pragma unroll
            for (int off = 32; off > 0; off >>= 1) v += __shfl_down(v, off);
            acc[i][j] = v;
        }
    if (lane == 0) {
#pragma unroll
        for (int i = 0; i < 4; ++i) {
            int node = node0 + wave * 4 + i;
            if (node >= n) continue;
            float v0 = acc[i][0] + b2[0];
            float v1 = acc[i][1] + b2[1];
            float v2 = acc[i][2] + b2[2];
            float nr = fmaxf(sqrtf(v0 * v0 + v1 * v1 + v2 * v2), 1e-12f);
            outp[(size_t)node * 3 + 0] = v0 / nr;
            outp[(size_t)node * 3 + 1] = v1 / nr;
            outp[(size_t)node * 3 + 2] = v2 / nr;
        }
    }
}

// ---------------- host-side dispatch helpers ----------------
static void launch_edge(int outC, const int* src, const int* dst, int E,
                        const float* xu, const float* xw, const float* cvec,
                        float* agg, hipStream_t stream)
{
    dim3 g(ceil_div((size_t)E * outC, 256));
    if (outC == 32)       feast_edge<32><<<g, 256, 0, stream>>>(src, dst, E, xu, xw, cvec, agg);
    else if (outC == 64)  feast_edge<64><<<g, 256, 0, stream>>>(src, dst, E, xu, xw, cvec, agg);
    else                  feast_edge<128><<<g, 256, 0, stream>>>(src, dst, E, xu, xw, cvec, agg);
}

static void launch_fin(int outC, const float* agg, const float* xw, const float* cvec,
                       const float* bias, const int* indeg, float* outp,
                       int n, int ldo, int col0, int act, hipStream_t stream)
{
    dim3 g(ceil_div((size_t)n * outC, 256));
    if (outC == 32)       feast_finalize<32><<<g, 256, 0, stream>>>(agg, xw, cvec, bias, indeg, outp, n, ldo, col0, act);
    else if (outC == 64)  feast_finalize<64><<<g, 256, 0, stream>>>(agg, xw, cvec, bias, indeg, outp, n, ldo, col0, act);
    else                  feast_finalize<128><<<g, 256, 0, stream>>>(agg, xw, cvec, bias, indeg, outp, n, ldo, col0, act);
}

extern "C" void kernel_launch(void* const* d_in, const int* in_sizes, int n_in,
                              void* d_out, int out_size, void* d_ws, size_t ws_size,
                              hipStream_t stream)
{
    const float* x      = (const float*)d_in[0];
    const int*   ei1    = (const int*)d_in[1];
    const int*   ei2    = (const int*)d_in[2];
    const int*   ei3    = (const int*)d_in[3];
    const int*   clust2 = (const int*)d_in[4];
    const int*   clust3 = (const int*)d_in[5];
    const float* lp[8][4];
    for (int i = 0; i < 8; ++i)
        for (int j = 0; j < 4; ++j)
            lp[i][j] = (const float*)d_in[6 + i * 4 + j];  // l1,l2,l3,l4,r1,r2,r3,r4 x {u,c,w,b}
    const float* fc1_w = (const float*)d_in[38];
    const float* fc1_b = (const float*)d_in[39];
    const float* fc2_w = (const float*)d_in[40];
    const float* fc2_b = (const float*)d_in[41];
    float* out = (float*)d_out;

    // ---- workspace layout (~206 MB) ----
    char* ws = (char*)d_ws;
    size_t off = 0;
    auto alloc = [&](size_t b) { size_t p = off; off += (b + 255) & ~(size_t)255; return p; };
    float* XW    = (float*)(ws + alloc((size_t)cN1 * NH * 32 * 4));  // 115.2 MB (max xw)
    float* AGG   = (float*)(ws + alloc((size_t)cN1 * 32 * 4));       // 12.8 MB
    float* GATH  = (float*)(ws + alloc((size_t)cN1 * 64 * 4));       // 25.6 MB (pool/gather scratch)
    float* X1CAT = (float*)(ws + alloc((size_t)cN1 * 64 * 4));       // 25.6 MB
    float* X2CAT = (float*)(ws + alloc((size_t)cN2 * 128 * 4));      // 12.8 MB
    float* X2B   = (float*)(ws + alloc((size_t)cN2 * 64 * 4));       // 6.4 MB
    float* X3    = (float*)(ws + alloc((size_t)cN3 * 128 * 4));      // 3.2 MB
    float* XU    = (float*)(ws + alloc((size_t)cN1 * NH * 4));       // 3.6 MB
    int* CNT1 = (int*)(ws + alloc((size_t)cN1 * 4));
    int* CNT2 = (int*)(ws + alloc((size_t)cN2 * 4));
    int* CNT3 = (int*)(ws + alloc((size_t)cN3 * 4));
    int* PC2  = (int*)(ws + alloc((size_t)cN2 * 4));
    int* PC3  = (int*)(ws + alloc((size_t)cN3 * 4));
    float* YB = GATH;  // r4 output aliases gather scratch (free by then)

    // ---- in-degrees (shared across feast calls per edge list) ----
    hipMemsetAsync(CNT1, 0, (size_t)cN1 * 4, stream);
    hipMemsetAsync(CNT2, 0, (size_t)cN2 * 4, stream);
    hipMemsetAsync(CNT3, 0, (size_t)cN3 * 4, stream);
    count_idx<<<ceil_div(cE1, 256), 256, 0, stream>>>(ei1 + cE1, cE1, CNT1);
    count_idx<<<ceil_div(cE2, 256), 256, 0, stream>>>(ei2 + cE2, cE2, CNT2);
    count_idx<<<ceil_div(cE3, 256), 256, 0, stream>>>(ei3 + cE3, cE3, CNT3);

    auto feast = [&](const float* xin, int ldx, int n, int cin, int outC,
                     const int* ei, int E, const int* indeg,
                     const float* const* L, float* dstp, int ldo, int col0, int act) {
        // xu = xin @ u  [n, 9]
        gemm_f32<<<dim3(1, ceil_div(n, 64)), 256, 0, stream>>>(xin, ldx, L[0], NH, XU, NH, n, NH, cin);
        // xw = xin @ W  [n, 9*outC]
        int NC = NH * outC;
        gemm_f32<<<dim3(ceil_div(NC, 64), ceil_div(n, 64)), 256, 0, stream>>>(xin, ldx, L[2], NC, XW, NC, n, NC, cin);
        hipMemsetAsync(AGG, 0, (size_t)n * outC * 4, stream);
        launch_edge(outC, ei, ei + E, E, XU, XW, L[1], AGG, stream);
        launch_fin(outC, AGG, XW, L[1], L[3], indeg, dstp, n, ldo, col0, act, stream);
    };

    // l1: [N1,6] -> [N1,32] into X1CAT[:, 0:32]
    feast(x, 6, cN1, 6, 32, ei1, cE1, CNT1, lp[0], X1CAT, 64, 0, 1);

    // pool -> [N2,32] in GATH
    hipMemsetAsync(PC2, 0, (size_t)cN2 * 4, stream);
    hipMemsetAsync(GATH, 0, (size_t)cN2 * 32 * 4, stream);
    count_idx<<<ceil_div(cN1, 256), 256, 0, stream>>>(clust2, cN1, PC2);
    pool_scatter<<<ceil_div((size_t)cN1 * 32, 256), 256, 0, stream>>>(X1CAT, 64, clust2, GATH, 32, cN1);
    pool_div<<<ceil_div((size_t)cN2 * 32, 256), 256, 0, stream>>>(GATH, PC2, 32, cN2);

    // l2: [N2,32] -> [N2,64] into X2CAT[:, 0:64]
    feast(GATH, 32, cN2, 32, 64, ei2, cE2, CNT2, lp[1], X2CAT, 128, 0, 1);

    // pool -> [N3,64] in GATH
    hipMemsetAsync(PC3, 0, (size_t)cN3 * 4, stream);
    hipMemsetAsync(GATH, 0, (size_t)cN3 * 64 * 4, stream);
    count_idx<<<ceil_div(cN2, 256), 256, 0, stream>>>(clust3, cN2, PC3);
    pool_scatter<<<ceil_div((size_t)cN2 * 64, 256), 256, 0, stream>>>(X2CAT, 128, clust3, GATH, 64, cN2);
    pool_div<<<ceil_div((size_t)cN3 * 64, 256), 256, 0, stream>>>(GATH, PC3, 64, cN3);

    // l3: [N3,64] -> [N3,128] into X3
    feast(GATH, 64, cN3, 64, 128, ei3, cE3, CNT3, lp[2], X3, 128, 0, 1);
    // l4: [N3,128] -> [N3,128] in-place (input consumed by GEMMs before finalize writes)
    feast(X3, 128, cN3, 128, 128, ei3, cE3, CNT3, lp[3], X3, 128, 0, 1);

    // r1: unpool x3 -> [N2,128], feast -> X2CAT[:, 64:128] (no act)
    gather_rows<<<ceil_div((size_t)cN2 * 128, 256), 256, 0, stream>>>(X3, 128, clust3, GATH, 128, cN2);
    feast(GATH, 128, cN2, 128, 64, ei2, cE2, CNT2, lp[4], X2CAT, 128, 64, 0);

    // r2: [N2,128] -> [N2,64] into X2B
    feast(X2CAT, 128, cN2, 128, 64, ei2, cE2, CNT2, lp[5], X2B, 64, 0, 1);

    // r3: unpool x2 -> [N1,64], feast -> X1CAT[:, 32:64] (no act)
    gather_rows<<<ceil_div((size_t)cN1 * 64, 256), 256, 0, stream>>>(X2B, 64, clust2, GATH, 64, cN1);
    feast(GATH, 64, cN1, 64, 32, ei1, cE1, CNT1, lp[6], X1CAT, 64, 32, 0);

    // r4: [N1,64] -> [N1,32] into YB
    feast(X1CAT, 64, cN1, 64, 32, ei1, cE1, CNT1, lp[7], YB, 32, 0, 1);

    // fused FC head + normalize
    fc_head<<<ceil_div(cN1, 16), 256, 0, stream>>>(YB, fc1_w, fc1_b, fc2_w, fc2_b, out, cN1);

    (void)in_sizes; (void)n_in; (void)out_size; (void)ws_size;
}